// Round 1
// 713.147 us; speedup vs baseline: 1.0368x; 1.0368x over previous
//
#include <hip/hip_runtime.h>
#include <math.h>

#define D 1024
#define EPS_COS 1e-8f
#define EP 0.001f

typedef float f32x4 __attribute__((ext_vector_type(4)));

// One 320-thread block (5 waves) per batch item.
// Item i owns 25 row-pairs: rows 0,1 -> (qpos,ipos)[2i+r], rows 2..24 -> (qneg,ineg)[23i+r-2].
// Wave w handles rows r = w, w+5, w+10, w+15, w+20  (exactly 5 each — balanced).
// Per row: 64 lanes x 4 float4 = 1024 floats per operand, streamed non-temporally
// (every byte is read exactly once — no reuse to cache).
__global__ __launch_bounds__(320) void fused_item_kernel(
    const float* __restrict__ qpos, const float* __restrict__ ipos,
    const float* __restrict__ qneg, const float* __restrict__ ineg,
    float* __restrict__ out)
{
    const int item = (int)blockIdx.x;
    const int wave = (int)(threadIdx.x >> 6);   // 0..4
    const int lane = (int)(threadIdx.x & 63);

    float psum = 0.f, nsum = 0.f;

#pragma unroll
    for (int rr = 0; rr < 5; ++rr) {
        const int r = wave + 5 * rr;            // 0..24, 5 per wave
        const float* a;
        const float* b;
        if (r < 2) {
            const size_t off = ((size_t)(2 * item + r)) * D;
            a = qpos + off;
            b = ipos + off;
        } else {
            const size_t off = ((size_t)(23 * item + (r - 2))) * D;
            a = qneg + off;
            b = ineg + off;
        }
        const f32x4* a4 = (const f32x4*)a + lane;
        const f32x4* b4 = (const f32x4*)b + lane;

        float dab = 0.f, daa = 0.f, dbb = 0.f;
#pragma unroll
        for (int j = 0; j < 4; ++j) {
            const f32x4 av = __builtin_nontemporal_load(&a4[64 * j]);
            const f32x4 bv = __builtin_nontemporal_load(&b4[64 * j]);
            dab += av.x * bv.x + av.y * bv.y + av.z * bv.z + av.w * bv.w;
            daa += av.x * av.x + av.y * av.y + av.z * av.z + av.w * av.w;
            dbb += bv.x * bv.x + bv.y * bv.y + bv.z * bv.z + bv.w * bv.w;
        }

        // 64-lane butterfly reduction (wave = 64 on CDNA)
#pragma unroll
        for (int off = 32; off > 0; off >>= 1) {
            dab += __shfl_down(dab, off, 64);
            daa += __shfl_down(daa, off, 64);
            dbb += __shfl_down(dbb, off, 64);
        }

        if (lane == 0) {
            const float denom = fmaxf(sqrtf(daa) * sqrtf(dbb), EPS_COS);
            const float ecs = __expf(dab / denom);
            if (r < 2) psum += ecs; else nsum += ecs;
        }
    }

    __shared__ float sp[5], sn[5];
    if (lane == 0) { sp[wave] = psum; sn[wave] = nsum; }
    __syncthreads();
    if (threadIdx.x == 0) {
        const float ps = sp[0] + sp[1] + sp[2] + sp[3] + sp[4];
        const float ns = sn[0] + sn[1] + sn[2] + sn[3] + sn[4];
        atomicAdd(out, (ns - ps) / (ps + ns + EP));
    }
}

extern "C" void kernel_launch(void* const* d_in, const int* in_sizes, int n_in,
                              void* d_out, int out_size, void* d_ws, size_t ws_size,
                              hipStream_t stream) {
    const float* qpos = (const float*)d_in[0];   // [2B, D]
    const float* qneg = (const float*)d_in[1];   // [23B, D]
    const float* ipos = (const float*)d_in[2];   // [2B, D]
    const float* ineg = (const float*)d_in[3];   // [23B, D]

    const int B = in_sizes[0] / (2 * D);         // 4096

    // d_out is poisoned to 0xAA before every timed launch — zero it.
    hipMemsetAsync(d_out, 0, sizeof(float), stream);

    // One block per batch item; 5 waves x 5 rows = 25 row-pairs per item.
    fused_item_kernel<<<B, 320, 0, stream>>>(qpos, ipos, qneg, ineg, (float*)d_out);
}